// Round 1
// baseline (228.248 us; speedup 1.0000x reference)
//
#include <hip/hip_runtime.h>

// RY(theta) single-qubit gate on batched state vector.
// state: [B=32, 2^20] fp32. Target qubit q (static=3) maps to flat-index
// bit (20-1-q) = 16, i.e. element stride 2^16. Butterfly per pair:
//   y0 = c*x0 - s*x1 ; y1 = s*x0 + c*x1 ; t=theta/2, c=cos t, s=sin t.
// Memory-bound: 256 MiB total traffic -> ~41 us floor at 6.3 TB/s.

__global__ __launch_bounds__(256) void ry_gate_kernel(
    const float* __restrict__ in,
    const float* __restrict__ theta,
    const int*   __restrict__ qubit,
    float*       __restrict__ out,
    unsigned int n_pairs4)   // number of float4 pairs = total_elems / 8
{
    unsigned int p = blockIdx.x * blockDim.x + threadIdx.x;
    if (p >= n_pairs4) return;

    // n = 20 total qubits (static per reference); target bit = 19 - qubit.
    const int shift = 19 - qubit[0];
    const unsigned int stride = 1u << shift;       // element stride (=65536 for q=3)
    const unsigned int mask   = stride - 1u;

    float t = theta[0] * 0.5f;
    float s, c;
    sincosf(t, &s, &c);

    // Enumerate only lower-half elements; splice pair index around target bit.
    unsigned int e  = p << 2;                      // float4 -> element index
    unsigned int i0 = (e & mask) | ((e & ~mask) << 1);
    unsigned int i1 = i0 + stride;

    const float4 x0 = *reinterpret_cast<const float4*>(in + i0);
    const float4 x1 = *reinterpret_cast<const float4*>(in + i1);

    float4 y0, y1;
    y0.x = c * x0.x - s * x1.x;  y1.x = s * x0.x + c * x1.x;
    y0.y = c * x0.y - s * x1.y;  y1.y = s * x0.y + c * x1.y;
    y0.z = c * x0.z - s * x1.z;  y1.z = s * x0.z + c * x1.z;
    y0.w = c * x0.w - s * x1.w;  y1.w = s * x0.w + c * x1.w;

    *reinterpret_cast<float4*>(out + i0) = y0;
    *reinterpret_cast<float4*>(out + i1) = y1;
}

// Scalar fallback for qubit close enough to the LSB that float4 pairing
// would straddle the pair boundary (stride < 4). Not hit for qubit=3 (n=20),
// but keeps the kernel correct for any static qubit.
__global__ __launch_bounds__(256) void ry_gate_kernel_scalar(
    const float* __restrict__ in,
    const float* __restrict__ theta,
    const int*   __restrict__ qubit,
    float*       __restrict__ out,
    unsigned int n_pairs)
{
    unsigned int p = blockIdx.x * blockDim.x + threadIdx.x;
    if (p >= n_pairs) return;

    const int shift = 19 - qubit[0];
    const unsigned int stride = 1u << shift;
    const unsigned int mask   = stride - 1u;

    float t = theta[0] * 0.5f;
    float s, c;
    sincosf(t, &s, &c);

    unsigned int i0 = (p & mask) | ((p & ~mask) << 1);
    unsigned int i1 = i0 + stride;

    float x0 = in[i0], x1 = in[i1];
    out[i0] = c * x0 - s * x1;
    out[i1] = s * x0 + c * x1;
}

extern "C" void kernel_launch(void* const* d_in, const int* in_sizes, int n_in,
                              void* d_out, int out_size, void* d_ws, size_t ws_size,
                              hipStream_t stream)
{
    const float* state = (const float*)d_in[0];
    const float* theta = (const float*)d_in[1];
    const int*   qubit = (const int*)d_in[2];
    float*       out   = (float*)d_out;

    const unsigned int n_total = (unsigned int)in_sizes[0];  // 32 * 2^20
    // qubit=3 is static in setup_inputs -> stride 2^16 >= 4: float4 path.
    const unsigned int n_pairs4 = n_total / 8u;
    const int block = 256;
    const unsigned int grid = (n_pairs4 + block - 1) / block;
    ry_gate_kernel<<<grid, block, 0, stream>>>(state, theta, qubit, out, n_pairs4);
}

// Round 2
// 227.387 us; speedup vs baseline: 1.0038x; 1.0038x over previous
//
#include <hip/hip_runtime.h>

// RY(theta) single-qubit gate on batched state vector.
// state: [B=32, 2^20] fp32. Target qubit q (static=3) maps to flat-index
// bit (20-1-q) = 16, i.e. element stride 2^16. Butterfly per pair:
//   y0 = c*x0 - s*x1 ; y1 = s*x0 + c*x1 ; t=theta/2, c=cos t, s=sin t.
// Memory-bound: 256 MiB total traffic -> ~41 us floor at 6.3 TB/s.
//
// R2: 2 float4s per side per thread (64 B/dir/thread) for MLP + less index
// math; nontemporal loads/stores (zero-reuse streaming, avoid LLC pollution).

typedef float floatx4 __attribute__((ext_vector_type(4)));

__global__ __launch_bounds__(256) void ry_gate_kernel(
    const float* __restrict__ in,
    const float* __restrict__ theta,
    const int*   __restrict__ qubit,
    float*       __restrict__ out,
    unsigned int n_groups)   // groups of 8 lower-half elements = total/16
{
    unsigned int p = blockIdx.x * blockDim.x + threadIdx.x;
    if (p >= n_groups) return;

    // n = 20 total qubits (static per reference); target bit = 19 - qubit.
    const int shift = 19 - qubit[0];
    const unsigned int stride = 1u << shift;       // element stride (65536 for q=3)
    const unsigned int mask   = stride - 1u;

    float t = theta[0] * 0.5f;
    float s, c;
    sincosf(t, &s, &c);

    // 8 consecutive lower-half elements per thread; splice around target bit.
    // Requires stride >= 8 (true for qubit<=16 at n=20; qubit=3 here).
    unsigned int e  = p << 3;
    unsigned int i0 = (e & mask) | ((e & ~mask) << 1);
    unsigned int i1 = i0 + stride;

    const floatx4* pa0 = reinterpret_cast<const floatx4*>(in + i0);
    const floatx4* pa1 = reinterpret_cast<const floatx4*>(in + i0 + 4);
    const floatx4* pb0 = reinterpret_cast<const floatx4*>(in + i1);
    const floatx4* pb1 = reinterpret_cast<const floatx4*>(in + i1 + 4);

    floatx4 a0 = __builtin_nontemporal_load(pa0);
    floatx4 a1 = __builtin_nontemporal_load(pa1);
    floatx4 b0 = __builtin_nontemporal_load(pb0);
    floatx4 b1 = __builtin_nontemporal_load(pb1);

    floatx4 y00 = c * a0 - s * b0;
    floatx4 y01 = c * a1 - s * b1;
    floatx4 y10 = s * a0 + c * b0;
    floatx4 y11 = s * a1 + c * b1;

    __builtin_nontemporal_store(y00, reinterpret_cast<floatx4*>(out + i0));
    __builtin_nontemporal_store(y01, reinterpret_cast<floatx4*>(out + i0 + 4));
    __builtin_nontemporal_store(y10, reinterpret_cast<floatx4*>(out + i1));
    __builtin_nontemporal_store(y11, reinterpret_cast<floatx4*>(out + i1 + 4));
}

// Scalar fallback (any qubit, incl. stride<8). Not used for qubit=3.
__global__ __launch_bounds__(256) void ry_gate_kernel_scalar(
    const float* __restrict__ in,
    const float* __restrict__ theta,
    const int*   __restrict__ qubit,
    float*       __restrict__ out,
    unsigned int n_pairs)
{
    unsigned int p = blockIdx.x * blockDim.x + threadIdx.x;
    if (p >= n_pairs) return;

    const int shift = 19 - qubit[0];
    const unsigned int stride = 1u << shift;
    const unsigned int mask   = stride - 1u;

    float t = theta[0] * 0.5f;
    float s, c;
    sincosf(t, &s, &c);

    unsigned int i0 = (p & mask) | ((p & ~mask) << 1);
    unsigned int i1 = i0 + stride;

    float x0 = in[i0], x1 = in[i1];
    out[i0] = c * x0 - s * x1;
    out[i1] = s * x0 + c * x1;
}

extern "C" void kernel_launch(void* const* d_in, const int* in_sizes, int n_in,
                              void* d_out, int out_size, void* d_ws, size_t ws_size,
                              hipStream_t stream)
{
    const float* state = (const float*)d_in[0];
    const float* theta = (const float*)d_in[1];
    const int*   qubit = (const int*)d_in[2];
    float*       out   = (float*)d_out;

    const unsigned int n_total  = (unsigned int)in_sizes[0];  // 32 * 2^20
    const unsigned int n_groups = n_total / 16u;              // 8 low elems/thread
    const int block = 256;
    const unsigned int grid = (n_groups + block - 1) / block;
    ry_gate_kernel<<<grid, block, 0, stream>>>(state, theta, qubit, out, n_groups);
}